// Round 16
// baseline (4611.424 us; speedup 1.0000x reference)
//
#include <hip/hip_runtime.h>
#include <hip/hip_bf16.h>

// GRU, T=512 B=64 D=512 H=1024.
// Round 16 = R15 (best: 4023us) + two latency cuts, no restructuring:
//  (1) out-stores moved INTO the phase-1 data batch (between h-loads and
//      x-prefetch): their HBM acks retire under vmcnt(8) concurrently with
//      the h round-trip, and never block a later flag check (vmcnt retires
//      in issue order, so counted waits could not skip them at the check).
//  (2) 2-deep pipelined poll loops (two flag loads in flight, vmcnt(1)
//      ping-pong): sampling period halves, detect overshoot drops ~RT/4.
// Grid 128 WGs (256 deadlocked in R14 -- co-residency cap). bf16 MFMA,
// fp32 accumulate, fp32 h master in owner-wave registers.

typedef __attribute__((ext_vector_type(8))) short bf16x8;
typedef __attribute__((ext_vector_type(4))) float f32x4;

#define NWG 128
#define TSTEPS 512

static __device__ __forceinline__ float sigmoidf_fast(float x) {
    return 1.0f / (1.0f + __expf(-x));
}

static __device__ __forceinline__ unsigned short float_to_bf16bits(float f) {
    __hip_bfloat16 b = __float2bfloat16(f);
    unsigned short us;
    __builtin_memcpy(&us, &b, 2);
    return us;
}

// coherent stores (write-through past L2, visible at memory-side LLC)
static __device__ __forceinline__ void store_coh_u16(void* p, unsigned short v) {
    unsigned vv = v;
    asm volatile("global_store_short %0, %1, off sc0 sc1"
                 :: "v"(p), "v"(vv) : "memory");
}
static __device__ __forceinline__ void store_coh_u32(unsigned* p, unsigned v) {
    asm volatile("global_store_dword %0, %1, off sc0 sc1"
                 :: "v"(p), "v"(v) : "memory");
}

__global__ __launch_bounds__(256) void k_convert_weights(
    const float* __restrict__ Wz, const float* __restrict__ Wr,
    const float* __restrict__ Wc,
    __hip_bfloat16* __restrict__ Wzr, __hip_bfloat16* __restrict__ Wcb)
{
    const long long NW = 1024LL * 1536LL;
    const long long stride = (long long)gridDim.x * blockDim.x;
    for (long long i = (long long)blockIdx.x * blockDim.x + threadIdx.x;
         i < 3 * NW; i += stride) {
        if (i < NW)            Wzr[i] = __float2bfloat16(Wz[i]);
        else if (i < 2 * NW)   Wzr[i] = __float2bfloat16(Wr[i - NW]);
        else                   Wcb[i - 2 * NW] = __float2bfloat16(Wc[i - 2 * NW]);
    }
}

__global__ __launch_bounds__(256) void k_convert_x(
    const float* __restrict__ x, __hip_bfloat16* __restrict__ xb)
{
    const long long N = 512LL * 64LL * 512LL;
    const long long stride = (long long)gridDim.x * blockDim.x;
    for (long long i = (long long)blockIdx.x * blockDim.x + threadIdx.x;
         i < N; i += stride)
        xb[i] = __float2bfloat16(x[i]);
}

__global__ __launch_bounds__(256) void k_init_h(
    const float* __restrict__ h0, __hip_bfloat16* __restrict__ hb)
{
    int i = blockIdx.x * blockDim.x + threadIdx.x;  // grid covers 64*1024
    hb[i] = __float2bfloat16(h0[i]);
}

// Persistent GRU: 128 WGs x 256 threads, 1 WG/CU (~100KB LDS).
// Domain dom=g&3 (batch quarter of 16 rows, 32 WGs, independent).
// wgid=g>>2: cols c0=wgid*32. Wave w: col-tile=w&1, K-half kh=w>>1.
// Owner waves (kh==0) hold z/h state, do epilogues, own flag slot wgid*2+tile.
__global__ __launch_bounds__(256, 1) void k_gru_persistent(
    const __hip_bfloat16* __restrict__ xb,   // [512][64][512] bf16
    const float* __restrict__ h0,            // [64][1024] f32
    __hip_bfloat16* __restrict__ hb_,        // [64][1024] bf16 publish of h
    const __hip_bfloat16* __restrict__ Wzr,  // [2048][1536] Wz rows, then Wr rows
    const __hip_bfloat16* __restrict__ Wcb,  // [1024][1536]
    const float* __restrict__ bz, const float* __restrict__ br,
    const float* __restrict__ bc,
    __hip_bfloat16* __restrict__ sb_,        // [64][1024] s = r*h (coherent)
    float* __restrict__ out,                 // [512][64][1024]
    unsigned* __restrict__ flags)            // [4][64] slots x 128B
{
    // x-part weights (K units 0..63) for 32 cols: [unit][row32][8], conflict-free
    __shared__ short w1z[64 * 32 * 8];    // 32KB
    __shared__ short w1r[64 * 32 * 8];    // 32KB
    __shared__ short w2c[64 * 32 * 8];    // 32KB
    __shared__ f32x4 red[2][2][64];       // 4KB cross-wave partial buffer

    short* hb = (short*)hb_;
    short* sb = (short*)sb_;

    const int g = blockIdx.x;
    const int lane = threadIdx.x & 63;
    const int wave = threadIdx.x >> 6;
    const int r15 = lane & 15;
    const int q = lane >> 4;        // 0..3
    const int kk = q << 3;          // per-lane K offset within 32-elem block

    const int dom = g & 3;               // sync domain = batch quarter
    const int wgid = g >> 2;             // 0..31 within domain
    const int c0 = wgid * 32;            // owned col base (32 cols)
    const int mt = dom * 16;             // domain batch base (16 rows)
    const int tile = wave & 1;           // col-tile within WG
    const int kh = wave >> 1;            // K-half (0 or 1)
    const int jcol = c0 + tile * 16 + r15;  // this wave's output col
    const int mb = mt + (q << 2);        // batch base for the 4 acc rows
    const bool owner = (kh == 0);        // epilogue/state-owning waves

    // flag slot per owner wave: slot = wgid*2 + tile; lane l polls slot l.
    unsigned* myslot = flags + (dom * 64 + wgid * 2 + tile) * 32;
    const unsigned* pollflag = flags + (dom * 64 + lane) * 32;

    // ---- stage x-part weights (units 0..63, 32 rows) into LDS, transposed
    for (int c = threadIdx.x; c < 64 * 32; c += 256) {
        int row = c & 31, blk = c >> 5;
        bf16x8 vz = *(const bf16x8*)((const short*)Wzr +
                                     (long long)(c0 + row) * 1536 + blk * 8);
        bf16x8 vr = *(const bf16x8*)((const short*)Wzr +
                                     (long long)(1024 + c0 + row) * 1536 + blk * 8);
        bf16x8 vc = *(const bf16x8*)((const short*)Wcb +
                                     (long long)(c0 + row) * 1536 + blk * 8);
        *(bf16x8*)(w1z + (blk * 32 + row) * 8) = vz;
        *(bf16x8*)(w1r + (blk * 32 + row) * 8) = vr;
        *(bf16x8*)(w2c + (blk * 32 + row) * 8) = vc;
    }

    // ---- recurrent-part weights (units 64..191, this wave's slice) in VGPRs
    bf16x8 wzh[16], wrh[16], wcs[16];     // 192 VGPR, step-invariant
#pragma unroll
    for (int i = 0; i < 16; ++i) {
        int bk = 64 + kh * 64 + i * 4 + q;
        wzh[i] = *(const bf16x8*)((const short*)Wzr +
                                  (long long)jcol * 1536 + bk * 8);
        wrh[i] = *(const bf16x8*)((const short*)Wzr +
                                  (long long)(1024 + jcol) * 1536 + bk * 8);
        wcs[i] = *(const bf16x8*)((const short*)Wcb +
                                  (long long)jcol * 1536 + bk * 8);
    }

    const float biasZ = bz[jcol];
    const float biasR = br[jcol];
    const float biasC = bc[jcol];

    // ---- fp32 h master in registers of owner waves (kh==0)
    float hreg[4];
    if (owner) {
#pragma unroll
        for (int v = 0; v < 4; ++v)
            hreg[v] = h0[(mb + v) * 1024 + jcol];
    }
    __syncthreads();

    float zreg[4] = {0.f, 0.f, 0.f, 0.f};

    // prologue: x fragments for t=0 (rows mt..mt+16, this wave's K-quarter)
    bf16x8 xc[8];
    {
        const short* Ax0 = (const short*)xb + (mt + r15) * 512 + kh * 256 + kk;
#pragma unroll
        for (int i = 0; i < 8; ++i)
            xc[i] = *(const bf16x8*)(Ax0 + i * 32);
    }

    for (int t = 0; t < TSTEPS; ++t) {
        // ================= Phase 1: z,r gates =================
        unsigned f1;
        asm volatile("global_load_dword %0, %1, off sc0 sc1"
                     : "=&v"(f1) : "v"(pollflag) : "memory");

        f32x4 zA = {0.f,0.f,0.f,0.f}, zB = {0.f,0.f,0.f,0.f};
        f32x4 rA = {0.f,0.f,0.f,0.f}, rB = {0.f,0.f,0.f,0.f};
#pragma unroll
        for (int i = 0; i < 8; ++i) {     // x-part: LDS weights, xc in regs
            int bk = kh * 32 + i * 4 + q;
            bf16x8 wz = *(const bf16x8*)(w1z + (bk * 32 + tile * 16 + r15) * 8);
            bf16x8 wr = *(const bf16x8*)(w1r + (bk * 32 + tile * 16 + r15) * 8);
            if (i & 1) { zB = __builtin_amdgcn_mfma_f32_16x16x32_bf16(xc[i], wz, zB, 0, 0, 0);
                         rB = __builtin_amdgcn_mfma_f32_16x16x32_bf16(xc[i], wr, rB, 0, 0, 0); }
            else       { zA = __builtin_amdgcn_mfma_f32_16x16x32_bf16(xc[i], wz, zA, 0, 0, 0);
                         rA = __builtin_amdgcn_mfma_f32_16x16x32_bf16(xc[i], wr, rA, 0, 0, 0); }
        }
        asm volatile("s_waitcnt vmcnt(0)" ::: "memory");
        __builtin_amdgcn_sched_barrier(0);
        unsigned pa1 = 0, pb1 = 0;        // pipelined poll regs (kept alive)
        {
            const unsigned gen = (unsigned)(2 * t);     // h(t-1) published
            if (!__all(f1 >= gen)) {
                asm volatile("global_load_dword %0, %1, off sc0 sc1"
                             : "=&v"(pa1) : "v"(pollflag) : "memory");
                asm volatile("global_load_dword %0, %1, off sc0 sc1"
                             : "=&v"(pb1) : "v"(pollflag) : "memory");
                for (;;) {
                    asm volatile("s_waitcnt vmcnt(1)" ::: "memory");
                    if (__all(pa1 >= gen)) break;
                    asm volatile("global_load_dword %0, %1, off sc0 sc1"
                                 : "=&v"(pa1) : "v"(pollflag) : "memory");
                    asm volatile("s_waitcnt vmcnt(1)" ::: "memory");
                    if (__all(pb1 >= gen)) break;
                    asm volatile("global_load_dword %0, %1, off sc0 sc1"
                                 : "=&v"(pb1) : "v"(pollflag) : "memory");
                }
            }
        }
        __builtin_amdgcn_sched_barrier(0);

        // data batch: 16 coherent h loads, then out-stores for t-1 (acks
        // retire under vmcnt(8) with the h RT), then 8 x-prefetch loads.
        bf16x8 fr[16], xn[8];
        {
            const short* Ah = hb + (mt + r15) * 1024 + kh * 512 + kk;
            const int tn = (t + 1 < TSTEPS) ? t + 1 : t;
            const short* AxN = (const short*)xb + (long long)tn * 64 * 512 +
                               (mt + r15) * 512 + kh * 256 + kk;
#pragma unroll
            for (int i = 0; i < 16; ++i)
                asm volatile("global_load_dwordx4 %0, %1, off sc0 sc1"
                             : "=&v"(fr[i]) : "v"(Ah + i * 32));
            if (owner && t > 0) {          // h(t-1) = current hreg
                float* outp = out + (long long)(t - 1) * 64 * 1024;
#pragma unroll
                for (int v = 0; v < 4; ++v)
                    asm volatile("global_store_dword %0, %1, off"
                                 :: "v"(outp + (mb + v) * 1024 + jcol),
                                    "v"(hreg[v]) : "memory");
            }
#pragma unroll
            for (int i = 0; i < 8; ++i)
                asm volatile("global_load_dwordx4 %0, %1, off"
                             : "=&v"(xn[i]) : "v"(AxN + i * 32));
            asm volatile("s_waitcnt vmcnt(8)" ::: "memory");
            __builtin_amdgcn_sched_barrier(0);
            asm volatile("" :: "v"(pa1), "v"(pb1));  // poll-reg keep-alive
        }
        // h-part: pure MFMA chain, weights in registers
#pragma unroll
        for (int i = 0; i < 16; ++i) {
            if (i & 1) { zB = __builtin_amdgcn_mfma_f32_16x16x32_bf16(fr[i], wzh[i], zB, 0, 0, 0);
                         rB = __builtin_amdgcn_mfma_f32_16x16x32_bf16(fr[i], wrh[i], rB, 0, 0, 0); }
            else       { zA = __builtin_amdgcn_mfma_f32_16x16x32_bf16(fr[i], wzh[i], zA, 0, 0, 0);
                         rA = __builtin_amdgcn_mfma_f32_16x16x32_bf16(fr[i], wrh[i], rA, 0, 0, 0); }
        }
        {
            f32x4 pz = zA + zB;
            f32x4 pr = rA + rB;
            if (!owner) { red[tile][0][lane] = pz; red[tile][1][lane] = pr; }
            __syncthreads();
            if (owner) {
                f32x4 oz = red[tile][0][lane];
                f32x4 orr = red[tile][1][lane];
                // s publish FIRST (on the critical path)...
#pragma unroll
                for (int v = 0; v < 4; ++v) {
                    float rv = sigmoidf_fast(pr[v] + orr[v] + biasR);
                    store_coh_u16(sb + (mb + v) * 1024 + jcol,
                                  float_to_bf16bits(rv * hreg[v]));  // fp32 h
                }
                // per-wave arrive: drain own stores, fire own flag (gen 2t+1)
                asm volatile("s_waitcnt vmcnt(0)" ::: "memory");
                if (lane == 0) store_coh_u32(myslot, (unsigned)(2 * t + 1));
                // ...z sigmoids after (consumed locally in phase 2)
#pragma unroll
                for (int v = 0; v < 4; ++v)
                    zreg[v] = sigmoidf_fast(pz[v] + oz[v] + biasZ);
            }
        }

        // ================= Phase 2: candidate + blend =================
        unsigned f2;
        asm volatile("global_load_dword %0, %1, off sc0 sc1"
                     : "=&v"(f2) : "v"(pollflag) : "memory");

        f32x4 cA = {0.f,0.f,0.f,0.f}, cB = {0.f,0.f,0.f,0.f};
#pragma unroll
        for (int i = 0; i < 8; ++i) {     // x-part: reuse xc fragments
            int bk = kh * 32 + i * 4 + q;
            bf16x8 wc = *(const bf16x8*)(w2c + (bk * 32 + tile * 16 + r15) * 8);
            if (i & 1) cB = __builtin_amdgcn_mfma_f32_16x16x32_bf16(xc[i], wc, cB, 0, 0, 0);
            else       cA = __builtin_amdgcn_mfma_f32_16x16x32_bf16(xc[i], wc, cA, 0, 0, 0);
        }
        asm volatile("s_waitcnt vmcnt(0)" ::: "memory");
        __builtin_amdgcn_sched_barrier(0);
        unsigned pa2 = 0, pb2 = 0;        // pipelined poll regs (kept alive)
        {
            const unsigned gen = (unsigned)(2 * t + 1);  // s published
            if (!__all(f2 >= gen)) {
                asm volatile("global_load_dword %0, %1, off sc0 sc1"
                             : "=&v"(pa2) : "v"(pollflag) : "memory");
                asm volatile("global_load_dword %0, %1, off sc0 sc1"
                             : "=&v"(pb2) : "v"(pollflag) : "memory");
                for (;;) {
                    asm volatile("s_waitcnt vmcnt(1)" ::: "memory");
                    if (__all(pa2 >= gen)) break;
                    asm volatile("global_load_dword %0, %1, off sc0 sc1"
                                 : "=&v"(pa2) : "v"(pollflag) : "memory");
                    asm volatile("s_waitcnt vmcnt(1)" ::: "memory");
                    if (__all(pb2 >= gen)) break;
                    asm volatile("global_load_dword %0, %1, off sc0 sc1"
                                 : "=&v"(pb2) : "v"(pollflag) : "memory");
                }
            }
        }
        __builtin_amdgcn_sched_barrier(0);

        {
            const short* As = sb + (mt + r15) * 1024 + kh * 512 + kk;
            bf16x8 fs[16];
#pragma unroll
            for (int i = 0; i < 16; ++i)
                asm volatile("global_load_dwordx4 %0, %1, off sc0 sc1"
                             : "=&v"(fs[i]) : "v"(As + i * 32));
            asm volatile("s_waitcnt vmcnt(0)" ::: "memory");
            __builtin_amdgcn_sched_barrier(0);
            asm volatile("" :: "v"(pa2), "v"(pb2));  // poll-reg keep-alive
#pragma unroll
            for (int i = 0; i < 16; ++i) {
                if (i & 1) cB = __builtin_amdgcn_mfma_f32_16x16x32_bf16(fs[i], wcs[i], cB, 0, 0, 0);
                else       cA = __builtin_amdgcn_mfma_f32_16x16x32_bf16(fs[i], wcs[i], cA, 0, 0, 0);
            }
            f32x4 pc = cA + cB;
            if (!owner) red[tile][0][lane] = pc;
            __syncthreads();
            if (owner) {
                f32x4 oc = red[tile][0][lane];
#pragma unroll
                for (int v = 0; v < 4; ++v) {
                    float cv = tanhf(pc[v] + oc[v] + biasC);
                    float h_new = (1.0f - zreg[v]) * hreg[v] + zreg[v] * cv;
                    hreg[v] = h_new;
                    store_coh_u16(hb + (mb + v) * 1024 + jcol,
                                  float_to_bf16bits(h_new));
                }
                // per-wave arrive: drain own stores, fire own flag (gen 2t+2)
                asm volatile("s_waitcnt vmcnt(0)" ::: "memory");
                if (lane == 0) store_coh_u32(myslot, (unsigned)(2 * t + 2));
            }
        }
        // rotate prefetched x (ordered after phase-2 vmcnt(0)+sched_barrier)
#pragma unroll
        for (int i = 0; i < 8; ++i) xc[i] = xn[i];
    }

    // tail: flush the final step's output rows (t = 511)
    if (owner) {
        float* outt = out + (long long)(TSTEPS - 1) * 64 * 1024;
#pragma unroll
        for (int v = 0; v < 4; ++v)
            outt[(mb + v) * 1024 + jcol] = hreg[v];
    }
}

extern "C" void kernel_launch(void* const* d_in, const int* in_sizes, int n_in,
                              void* d_out, int out_size, void* d_ws, size_t ws_size,
                              hipStream_t stream)
{
    (void)in_sizes; (void)n_in; (void)out_size; (void)ws_size;
    const float* x  = (const float*)d_in[0];
    const float* h0 = (const float*)d_in[1];
    const float* Wz = (const float*)d_in[2];
    const float* bz = (const float*)d_in[3];
    const float* Wr = (const float*)d_in[4];
    const float* br = (const float*)d_in[5];
    const float* Wc = (const float*)d_in[6];
    const float* bc = (const float*)d_in[7];
    float* out = (float*)d_out;

    // ws layout (bytes, 256-aligned): total ~43.3 MB
    char* ws = (char*)d_ws;
    __hip_bfloat16* Wzr = (__hip_bfloat16*)(ws);              // [2048][1536] bf16
    __hip_bfloat16* Wcb = (__hip_bfloat16*)(ws + 6291456);    // [1024][1536] bf16
    __hip_bfloat16* xb  = (__hip_bfloat16*)(ws + 9437184);    // [512][64][512] bf16
    __hip_bfloat16* hb  = (__hip_bfloat16*)(ws + 42991616);   // [64][1024] bf16
    __hip_bfloat16* sb  = (__hip_bfloat16*)(ws + 43122688);   // [64][1024] bf16
    unsigned*    flags  = (unsigned*)(ws + 43253760);         // 4*64 slots x 128B

    k_convert_weights<<<1024, 256, 0, stream>>>(Wz, Wr, Wc, Wzr, Wcb);
    k_convert_x<<<2048, 256, 0, stream>>>(x, xb);
    k_init_h<<<256, 256, 0, stream>>>(h0, hb);
    (void)hipMemsetAsync(flags, 0, 4 * 64 * 32 * sizeof(unsigned), stream);

    k_gru_persistent<<<NWG, 256, 0, stream>>>(
        xb, h0, hb, Wzr, Wcb, bz, br, bc, sb, out, flags);
}

// Round 17
// 4006.299 us; speedup vs baseline: 1.1510x; 1.1510x over previous
//
#include <hip/hip_runtime.h>
#include <hip/hip_bf16.h>

// GRU, T=512 B=64 D=512 H=1024.
// Round 17 = exact revert to R15 (best: 4023us). R16's two "optimizations"
// regressed (-15%): (a) out-stores interleaved into the data batch forced
// vmcnt(8) to retire their acks before the h-MFMAs (vmcnt retires in issue
// order; plain stores ack fast at L2, so they were FREE where R15 had them);
// (b) 2-deep pipelined poll added miss-path overhead.
// Structure: 4 independent sync domains x 32 WGs (batch quarters);
// conflict-free transposed x-part weights in LDS; recurrent weights in VGPRs
// (192/wave, step-invariant); speculative flag pre-check under the x-part
// MFMAs; single 16-fragment coherent data batch + 8 x-prefetch under
// counted vmcnt(8); per-wave arrive flags; fp32 h master in owner registers.

typedef __attribute__((ext_vector_type(8))) short bf16x8;
typedef __attribute__((ext_vector_type(4))) float f32x4;

#define NWG 128
#define TSTEPS 512

static __device__ __forceinline__ float sigmoidf_fast(float x) {
    return 1.0f / (1.0f + __expf(-x));
}

static __device__ __forceinline__ unsigned short float_to_bf16bits(float f) {
    __hip_bfloat16 b = __float2bfloat16(f);
    unsigned short us;
    __builtin_memcpy(&us, &b, 2);
    return us;
}

// coherent stores (write-through past L2, visible at memory-side LLC)
static __device__ __forceinline__ void store_coh_u16(void* p, unsigned short v) {
    unsigned vv = v;
    asm volatile("global_store_short %0, %1, off sc0 sc1"
                 :: "v"(p), "v"(vv) : "memory");
}
static __device__ __forceinline__ void store_coh_u32(unsigned* p, unsigned v) {
    asm volatile("global_store_dword %0, %1, off sc0 sc1"
                 :: "v"(p), "v"(v) : "memory");
}

__global__ __launch_bounds__(256) void k_convert_weights(
    const float* __restrict__ Wz, const float* __restrict__ Wr,
    const float* __restrict__ Wc,
    __hip_bfloat16* __restrict__ Wzr, __hip_bfloat16* __restrict__ Wcb)
{
    const long long NW = 1024LL * 1536LL;
    const long long stride = (long long)gridDim.x * blockDim.x;
    for (long long i = (long long)blockIdx.x * blockDim.x + threadIdx.x;
         i < 3 * NW; i += stride) {
        if (i < NW)            Wzr[i] = __float2bfloat16(Wz[i]);
        else if (i < 2 * NW)   Wzr[i] = __float2bfloat16(Wr[i - NW]);
        else                   Wcb[i - 2 * NW] = __float2bfloat16(Wc[i - 2 * NW]);
    }
}

__global__ __launch_bounds__(256) void k_convert_x(
    const float* __restrict__ x, __hip_bfloat16* __restrict__ xb)
{
    const long long N = 512LL * 64LL * 512LL;
    const long long stride = (long long)gridDim.x * blockDim.x;
    for (long long i = (long long)blockIdx.x * blockDim.x + threadIdx.x;
         i < N; i += stride)
        xb[i] = __float2bfloat16(x[i]);
}

__global__ __launch_bounds__(256) void k_init_h(
    const float* __restrict__ h0, __hip_bfloat16* __restrict__ hb)
{
    int i = blockIdx.x * blockDim.x + threadIdx.x;  // grid covers 64*1024
    hb[i] = __float2bfloat16(h0[i]);
}

// Persistent GRU: 128 WGs x 256 threads, 1 WG/CU (~100KB LDS).
// Domain dom=g&3 (batch quarter of 16 rows, 32 WGs, independent).
// wgid=g>>2: cols c0=wgid*32. Wave w: col-tile=w&1, K-half kh=w>>1.
// Owner waves (kh==0) hold z/h state, do epilogues, own flag slot wgid*2+tile.
__global__ __launch_bounds__(256, 1) void k_gru_persistent(
    const __hip_bfloat16* __restrict__ xb,   // [512][64][512] bf16
    const float* __restrict__ h0,            // [64][1024] f32
    __hip_bfloat16* __restrict__ hb_,        // [64][1024] bf16 publish of h
    const __hip_bfloat16* __restrict__ Wzr,  // [2048][1536] Wz rows, then Wr rows
    const __hip_bfloat16* __restrict__ Wcb,  // [1024][1536]
    const float* __restrict__ bz, const float* __restrict__ br,
    const float* __restrict__ bc,
    __hip_bfloat16* __restrict__ sb_,        // [64][1024] s = r*h (coherent)
    float* __restrict__ out,                 // [512][64][1024]
    unsigned* __restrict__ flags)            // [4][64] slots x 128B
{
    // x-part weights (K units 0..63) for 32 cols: [unit][row32][8], conflict-free
    __shared__ short w1z[64 * 32 * 8];    // 32KB
    __shared__ short w1r[64 * 32 * 8];    // 32KB
    __shared__ short w2c[64 * 32 * 8];    // 32KB
    __shared__ f32x4 red[2][2][64];       // 4KB cross-wave partial buffer

    short* hb = (short*)hb_;
    short* sb = (short*)sb_;

    const int g = blockIdx.x;
    const int lane = threadIdx.x & 63;
    const int wave = threadIdx.x >> 6;
    const int r15 = lane & 15;
    const int q = lane >> 4;        // 0..3
    const int kk = q << 3;          // per-lane K offset within 32-elem block

    const int dom = g & 3;               // sync domain = batch quarter
    const int wgid = g >> 2;             // 0..31 within domain
    const int c0 = wgid * 32;            // owned col base (32 cols)
    const int mt = dom * 16;             // domain batch base (16 rows)
    const int tile = wave & 1;           // col-tile within WG
    const int kh = wave >> 1;            // K-half (0 or 1)
    const int jcol = c0 + tile * 16 + r15;  // this wave's output col
    const int mb = mt + (q << 2);        // batch base for the 4 acc rows
    const bool owner = (kh == 0);        // epilogue/state-owning waves

    // flag slot per owner wave: slot = wgid*2 + tile; lane l polls slot l.
    unsigned* myslot = flags + (dom * 64 + wgid * 2 + tile) * 32;
    const unsigned* pollflag = flags + (dom * 64 + lane) * 32;

    // ---- stage x-part weights (units 0..63, 32 rows) into LDS, transposed
    for (int c = threadIdx.x; c < 64 * 32; c += 256) {
        int row = c & 31, blk = c >> 5;
        bf16x8 vz = *(const bf16x8*)((const short*)Wzr +
                                     (long long)(c0 + row) * 1536 + blk * 8);
        bf16x8 vr = *(const bf16x8*)((const short*)Wzr +
                                     (long long)(1024 + c0 + row) * 1536 + blk * 8);
        bf16x8 vc = *(const bf16x8*)((const short*)Wcb +
                                     (long long)(c0 + row) * 1536 + blk * 8);
        *(bf16x8*)(w1z + (blk * 32 + row) * 8) = vz;
        *(bf16x8*)(w1r + (blk * 32 + row) * 8) = vr;
        *(bf16x8*)(w2c + (blk * 32 + row) * 8) = vc;
    }

    // ---- recurrent-part weights (units 64..191, this wave's slice) in VGPRs
    bf16x8 wzh[16], wrh[16], wcs[16];     // 192 VGPR, step-invariant
#pragma unroll
    for (int i = 0; i < 16; ++i) {
        int bk = 64 + kh * 64 + i * 4 + q;
        wzh[i] = *(const bf16x8*)((const short*)Wzr +
                                  (long long)jcol * 1536 + bk * 8);
        wrh[i] = *(const bf16x8*)((const short*)Wzr +
                                  (long long)(1024 + jcol) * 1536 + bk * 8);
        wcs[i] = *(const bf16x8*)((const short*)Wcb +
                                  (long long)jcol * 1536 + bk * 8);
    }

    const float biasZ = bz[jcol];
    const float biasR = br[jcol];
    const float biasC = bc[jcol];

    // ---- fp32 h master in registers of owner waves (kh==0)
    float hreg[4];
    if (owner) {
#pragma unroll
        for (int v = 0; v < 4; ++v)
            hreg[v] = h0[(mb + v) * 1024 + jcol];
    }
    __syncthreads();

    float zreg[4] = {0.f, 0.f, 0.f, 0.f};

    // prologue: x fragments for t=0 (rows mt..mt+16, this wave's K-quarter)
    bf16x8 xc[8];
    {
        const short* Ax0 = (const short*)xb + (mt + r15) * 512 + kh * 256 + kk;
#pragma unroll
        for (int i = 0; i < 8; ++i)
            xc[i] = *(const bf16x8*)(Ax0 + i * 32);
    }

    for (int t = 0; t < TSTEPS; ++t) {
        // ================= Phase 1: z,r gates =================
        unsigned f1;
        asm volatile("global_load_dword %0, %1, off sc0 sc1"
                     : "=&v"(f1) : "v"(pollflag) : "memory");

        f32x4 zA = {0.f,0.f,0.f,0.f}, zB = {0.f,0.f,0.f,0.f};
        f32x4 rA = {0.f,0.f,0.f,0.f}, rB = {0.f,0.f,0.f,0.f};
#pragma unroll
        for (int i = 0; i < 8; ++i) {     // x-part: LDS weights, xc in regs
            int bk = kh * 32 + i * 4 + q;
            bf16x8 wz = *(const bf16x8*)(w1z + (bk * 32 + tile * 16 + r15) * 8);
            bf16x8 wr = *(const bf16x8*)(w1r + (bk * 32 + tile * 16 + r15) * 8);
            if (i & 1) { zB = __builtin_amdgcn_mfma_f32_16x16x32_bf16(xc[i], wz, zB, 0, 0, 0);
                         rB = __builtin_amdgcn_mfma_f32_16x16x32_bf16(xc[i], wr, rB, 0, 0, 0); }
            else       { zA = __builtin_amdgcn_mfma_f32_16x16x32_bf16(xc[i], wz, zA, 0, 0, 0);
                         rA = __builtin_amdgcn_mfma_f32_16x16x32_bf16(xc[i], wr, rA, 0, 0, 0); }
        }
        asm volatile("s_waitcnt vmcnt(0)" ::: "memory");
        __builtin_amdgcn_sched_barrier(0);
        {
            const unsigned gen = (unsigned)(2 * t);     // h(t-1) published
            if (!__all(f1 >= gen)) {
                bool ok;
                do {
                    unsigned fv;
                    asm volatile("global_load_dword %0, %1, off sc0 sc1\n\t"
                                 "s_waitcnt vmcnt(0)"
                                 : "=&v"(fv) : "v"(pollflag) : "memory");
                    ok = (fv >= gen);
                } while (__any(!ok));
            }
        }
        __builtin_amdgcn_sched_barrier(0);

        // data batch: 16 coherent h loads + 8 plain next-x prefetch loads.
        // counted vmcnt(8): h-MFMAs start when the 16 h loads land; the 8
        // x-prefetch loads stay in flight.
        bf16x8 fr[16], xn[8];
        {
            const short* Ah = hb + (mt + r15) * 1024 + kh * 512 + kk;
            const int tn = (t + 1 < TSTEPS) ? t + 1 : t;
            const short* AxN = (const short*)xb + (long long)tn * 64 * 512 +
                               (mt + r15) * 512 + kh * 256 + kk;
#pragma unroll
            for (int i = 0; i < 16; ++i)
                asm volatile("global_load_dwordx4 %0, %1, off sc0 sc1"
                             : "=&v"(fr[i]) : "v"(Ah + i * 32));
#pragma unroll
            for (int i = 0; i < 8; ++i)
                asm volatile("global_load_dwordx4 %0, %1, off"
                             : "=&v"(xn[i]) : "v"(AxN + i * 32));
            asm volatile("s_waitcnt vmcnt(8)" ::: "memory");
            __builtin_amdgcn_sched_barrier(0);
        }
        // h-part: pure MFMA chain, weights in registers
#pragma unroll
        for (int i = 0; i < 16; ++i) {
            if (i & 1) { zB = __builtin_amdgcn_mfma_f32_16x16x32_bf16(fr[i], wzh[i], zB, 0, 0, 0);
                         rB = __builtin_amdgcn_mfma_f32_16x16x32_bf16(fr[i], wrh[i], rB, 0, 0, 0); }
            else       { zA = __builtin_amdgcn_mfma_f32_16x16x32_bf16(fr[i], wzh[i], zA, 0, 0, 0);
                         rA = __builtin_amdgcn_mfma_f32_16x16x32_bf16(fr[i], wrh[i], rA, 0, 0, 0); }
        }
        {
            f32x4 pz = zA + zB;
            f32x4 pr = rA + rB;
            if (!owner) { red[tile][0][lane] = pz; red[tile][1][lane] = pr; }
            __syncthreads();
            if (owner) {
                f32x4 oz = red[tile][0][lane];
                f32x4 orr = red[tile][1][lane];
                // s publish FIRST (on the critical path)...
#pragma unroll
                for (int v = 0; v < 4; ++v) {
                    float rv = sigmoidf_fast(pr[v] + orr[v] + biasR);
                    store_coh_u16(sb + (mb + v) * 1024 + jcol,
                                  float_to_bf16bits(rv * hreg[v]));  // fp32 h
                }
                // per-wave arrive: drain own stores, fire own flag (gen 2t+1)
                asm volatile("s_waitcnt vmcnt(0)" ::: "memory");
                if (lane == 0) store_coh_u32(myslot, (unsigned)(2 * t + 1));
                // ...z sigmoids after (consumed locally in phase 2)
#pragma unroll
                for (int v = 0; v < 4; ++v)
                    zreg[v] = sigmoidf_fast(pz[v] + oz[v] + biasZ);
            }
        }

        // ================= Phase 2: candidate + blend =================
        unsigned f2;
        asm volatile("global_load_dword %0, %1, off sc0 sc1"
                     : "=&v"(f2) : "v"(pollflag) : "memory");

        f32x4 cA = {0.f,0.f,0.f,0.f}, cB = {0.f,0.f,0.f,0.f};
#pragma unroll
        for (int i = 0; i < 8; ++i) {     // x-part: reuse xc fragments
            int bk = kh * 32 + i * 4 + q;
            bf16x8 wc = *(const bf16x8*)(w2c + (bk * 32 + tile * 16 + r15) * 8);
            if (i & 1) cB = __builtin_amdgcn_mfma_f32_16x16x32_bf16(xc[i], wc, cB, 0, 0, 0);
            else       cA = __builtin_amdgcn_mfma_f32_16x16x32_bf16(xc[i], wc, cA, 0, 0, 0);
        }
        asm volatile("s_waitcnt vmcnt(0)" ::: "memory");
        __builtin_amdgcn_sched_barrier(0);
        {
            const unsigned gen = (unsigned)(2 * t + 1);  // s published
            if (!__all(f2 >= gen)) {
                bool ok;
                do {
                    unsigned fv;
                    asm volatile("global_load_dword %0, %1, off sc0 sc1\n\t"
                                 "s_waitcnt vmcnt(0)"
                                 : "=&v"(fv) : "v"(pollflag) : "memory");
                    ok = (fv >= gen);
                } while (__any(!ok));
            }
        }
        __builtin_amdgcn_sched_barrier(0);

        {
            const short* As = sb + (mt + r15) * 1024 + kh * 512 + kk;
            bf16x8 fs[16];
#pragma unroll
            for (int i = 0; i < 16; ++i)
                asm volatile("global_load_dwordx4 %0, %1, off sc0 sc1"
                             : "=&v"(fs[i]) : "v"(As + i * 32));
            asm volatile("s_waitcnt vmcnt(0)" ::: "memory");
            __builtin_amdgcn_sched_barrier(0);
#pragma unroll
            for (int i = 0; i < 16; ++i) {
                if (i & 1) cB = __builtin_amdgcn_mfma_f32_16x16x32_bf16(fs[i], wcs[i], cB, 0, 0, 0);
                else       cA = __builtin_amdgcn_mfma_f32_16x16x32_bf16(fs[i], wcs[i], cA, 0, 0, 0);
            }
            f32x4 pc = cA + cB;
            if (!owner) red[tile][0][lane] = pc;
            __syncthreads();
            if (owner) {
                f32x4 oc = red[tile][0][lane];
#pragma unroll
                for (int v = 0; v < 4; ++v) {
                    float cv = tanhf(pc[v] + oc[v] + biasC);
                    float h_new = (1.0f - zreg[v]) * hreg[v] + zreg[v] * cv;
                    hreg[v] = h_new;
                    store_coh_u16(hb + (mb + v) * 1024 + jcol,
                                  float_to_bf16bits(h_new));
                }
                // per-wave arrive: drain own stores, fire own flag (gen 2t+2)
                asm volatile("s_waitcnt vmcnt(0)" ::: "memory");
                if (lane == 0) store_coh_u32(myslot, (unsigned)(2 * t + 2));
                // deferred HBM output stores (plain: ack at local L2 fast,
                // fully retired before the next flag RT completes)
                float* outt = out + (long long)t * 64 * 1024;
#pragma unroll
                for (int v = 0; v < 4; ++v)
                    outt[(mb + v) * 1024 + jcol] = hreg[v];
            }
        }
        // rotate prefetched x (ordered after phase-2 vmcnt(0)+sched_barrier)
#pragma unroll
        for (int i = 0; i < 8; ++i) xc[i] = xn[i];
    }
}

extern "C" void kernel_launch(void* const* d_in, const int* in_sizes, int n_in,
                              void* d_out, int out_size, void* d_ws, size_t ws_size,
                              hipStream_t stream)
{
    (void)in_sizes; (void)n_in; (void)out_size; (void)ws_size;
    const float* x  = (const float*)d_in[0];
    const float* h0 = (const float*)d_in[1];
    const float* Wz = (const float*)d_in[2];
    const float* bz = (const float*)d_in[3];
    const float* Wr = (const float*)d_in[4];
    const float* br = (const float*)d_in[5];
    const float* Wc = (const float*)d_in[6];
    const float* bc = (const float*)d_in[7];
    float* out = (float*)d_out;

    // ws layout (bytes, 256-aligned): total ~43.3 MB
    char* ws = (char*)d_ws;
    __hip_bfloat16* Wzr = (__hip_bfloat16*)(ws);              // [2048][1536] bf16
    __hip_bfloat16* Wcb = (__hip_bfloat16*)(ws + 6291456);    // [1024][1536] bf16
    __hip_bfloat16* xb  = (__hip_bfloat16*)(ws + 9437184);    // [512][64][512] bf16
    __hip_bfloat16* hb  = (__hip_bfloat16*)(ws + 42991616);   // [64][1024] bf16
    __hip_bfloat16* sb  = (__hip_bfloat16*)(ws + 43122688);   // [64][1024] bf16
    unsigned*    flags  = (unsigned*)(ws + 43253760);         // 4*64 slots x 128B

    k_convert_weights<<<1024, 256, 0, stream>>>(Wz, Wr, Wc, Wzr, Wcb);
    k_convert_x<<<2048, 256, 0, stream>>>(x, xb);
    k_init_h<<<256, 256, 0, stream>>>(h0, hb);
    (void)hipMemsetAsync(flags, 0, 4 * 64 * 32 * sizeof(unsigned), stream);

    k_gru_persistent<<<NWG, 256, 0, stream>>>(
        xb, h0, hb, Wzr, Wcb, bz, br, bc, sb, out, flags);
}